// Round 6
// baseline (480.676 us; speedup 1.0000x reference)
//
#include <hip/hip_runtime.h>

typedef __bf16 bf16x8 __attribute__((ext_vector_type(8)));
typedef __bf16 bf16x4 __attribute__((ext_vector_type(4)));
typedef float f32x4 __attribute__((ext_vector_type(4)));

#define LN_EPS 1e-5f

// async global->LDS, 16B per lane (wave-uniform LDS base + lane*16)
__device__ __forceinline__ void gl2lds16(const void* g, void* l) {
  __builtin_amdgcn_global_load_lds(
      (const __attribute__((address_space(1))) unsigned int*)g,
      (__attribute__((address_space(3))) unsigned int*)l, 16, 0, 0);
}

// -------- weight transpose + downcast: in f32 [R][C] -> out bf16 [C][R] --------
__global__ __launch_bounds__(256) void transpose_k(const float* __restrict__ in,
                                                   __bf16* __restrict__ out,
                                                   int R, int C) {
  __shared__ __bf16 t[32][33];
  int tx = threadIdx.x & 31, ty = threadIdx.x >> 5;  // 32x8
  int c = blockIdx.x * 32 + tx;
  for (int j = 0; j < 4; j++) {
    int r = blockIdx.y * 32 + ty + j * 8;
    t[ty + j * 8][tx] = (__bf16)in[(size_t)r * C + c];
  }
  __syncthreads();
  int r2 = blockIdx.y * 32 + tx;
  for (int j = 0; j < 4; j++) {
    int c2 = blockIdx.x * 32 + ty + j * 8;
    out[(size_t)c2 * R + r2] = t[tx][ty + j * 8];
  }
}

// -------- V transpose: qkv[token][2304] V-part -> vt[(b*12+h)*64+d][2048] --------
__global__ __launch_bounds__(256) void transpose_v(const __bf16* __restrict__ qkv,
                                                   __bf16* __restrict__ vt) {
  __shared__ __bf16 t[32][33];
  int bh = blockIdx.z;
  int b = bh / 12, h = bh % 12;
  int n0 = blockIdx.x * 32, d0 = blockIdx.y * 32;
  int tx = threadIdx.x & 31, ty = threadIdx.x >> 5;
  for (int j = 0; j < 4; j++) {
    int n = n0 + ty + j * 8;
    t[ty + j * 8][tx] = qkv[(size_t)(b * 2048 + n) * 2304 + 1536 + h * 64 + d0 + tx];
  }
  __syncthreads();
  for (int j = 0; j < 4; j++) {
    int d = d0 + ty + j * 8;
    vt[((size_t)bh * 64 + d) * 2048 + n0 + tx] = t[tx][ty + j * 8];
  }
}

// -------- layernorm over 768: f32 in -> bf16 out, one block per row --------
__global__ __launch_bounds__(256) void ln_kernel(const float* __restrict__ x,
                                                 const float* __restrict__ g,
                                                 const float* __restrict__ bta,
                                                 __bf16* __restrict__ out) {
  int row = blockIdx.x;
  size_t base = (size_t)row * 768;
  int t = threadIdx.x;
  float v[3];
  float s = 0.f, s2 = 0.f;
  for (int k = 0; k < 3; k++) {
    float f = x[base + t + k * 256];
    v[k] = f;
    s += f;
    s2 += f * f;
  }
  for (int m = 1; m < 64; m <<= 1) {
    s += __shfl_xor(s, m, 64);
    s2 += __shfl_xor(s2, m, 64);
  }
  __shared__ float sm[4][2];
  int wid = t >> 6, lane = t & 63;
  if (lane == 0) { sm[wid][0] = s; sm[wid][1] = s2; }
  __syncthreads();
  s = sm[0][0] + sm[1][0] + sm[2][0] + sm[3][0];
  s2 = sm[0][1] + sm[1][1] + sm[2][1] + sm[3][1];
  float mu = s * (1.f / 768.f);
  float var = s2 * (1.f / 768.f) - mu * mu;
  float rstd = rsqrtf(var + LN_EPS);
  for (int k = 0; k < 3; k++) {
    int c = t + k * 256;
    out[base + c] = (__bf16)((v[k] - mu) * rstd * g[c] + bta[c]);
  }
}

// -------- MFMA GEMM 128x128 (m97 structure), for N=768 GEMMs --------
// EPI 0: bf16 out = c ; EPI 1: bf16 poly-gelu ; EPI 2: f32 out = c + res
template <int EPI>
__global__ __launch_bounds__(256) void gemm128(const __bf16* __restrict__ A,
                                               const __bf16* __restrict__ BT,
                                               const float* __restrict__ bias,
                                               const float* __restrict__ res,
                                               void* __restrict__ outv,
                                               int M, int N, int K,
                                               const float* __restrict__ c0p,
                                               const float* __restrict__ c1p,
                                               const float* __restrict__ c2p) {
  __shared__ __bf16 As[128][32];  // UNPADDED: global_load_lds lane mapping
  __shared__ __bf16 Bs[128][32];
  int tid = threadIdx.x;
  int lane = tid & 63, wid = tid >> 6;
  int wr = wid >> 1, wc = wid & 1;
  int m0 = blockIdx.y * 128, n0 = blockIdx.x * 128;
  int mr = lane & 15, kq = (lane >> 4) * 8;
  int srow = tid >> 2, scol = (tid & 3) * 8;

  f32x4 acc[4][4] = {};

  for (int k0 = 0; k0 < K; k0 += 32) {
    for (int i = 0; i < 2; i++) {
      int row = srow + i * 64;
      gl2lds16(&A[(size_t)(m0 + row) * K + k0 + scol], &As[row][scol]);
      gl2lds16(&BT[(size_t)(n0 + row) * K + k0 + scol], &Bs[row][scol]);
    }
    __syncthreads();
    bf16x8 af[4], bfr[4];
    for (int i = 0; i < 4; i++) af[i] = *(bf16x8*)&As[wr * 64 + i * 16 + mr][kq];
    for (int j = 0; j < 4; j++) bfr[j] = *(bf16x8*)&Bs[wc * 64 + j * 16 + mr][kq];
    for (int i = 0; i < 4; i++)
      for (int j = 0; j < 4; j++)
        acc[i][j] = __builtin_amdgcn_mfma_f32_16x16x32_bf16(af[i], bfr[j], acc[i][j], 0, 0, 0);
    __syncthreads();
  }

  float ga = 0.f, gb = 0.f, gc = 0.f;
  if (EPI == 1) { ga = *c0p; gb = *c1p; gc = *c2p; }

  for (int i = 0; i < 4; i++) {
    for (int j = 0; j < 4; j++) {
      int col = n0 + wc * 64 + j * 16 + mr;
      float bv = bias[col];
      for (int r = 0; r < 4; r++) {
        int row = m0 + wr * 64 + i * 16 + (lane >> 4) * 4 + r;
        size_t idx = (size_t)row * N + col;
        float c = acc[i][j][r] + bv;
        if (EPI == 0) {
          ((__bf16*)outv)[idx] = (__bf16)c;
        } else if (EPI == 1) {
          float u = (ga * c + gb) * c + gc;
          ((__bf16*)outv)[idx] = (__bf16)u;
        } else {
          ((float*)outv)[idx] = c + res[idx];
        }
      }
    }
  }
}

// -------- MFMA GEMM 128x256 tile, 4x8 acc/wave: 0.375 KB LDS per MFMA --------
template <int EPI>
__global__ __launch_bounds__(256, 2) void gemm256(const __bf16* __restrict__ A,
                                                  const __bf16* __restrict__ BT,
                                                  const float* __restrict__ bias,
                                                  void* __restrict__ outv,
                                                  int M, int N, int K,
                                                  const float* __restrict__ c0p,
                                                  const float* __restrict__ c1p,
                                                  const float* __restrict__ c2p) {
  __shared__ __bf16 As[128][32];  // 8 KB
  __shared__ __bf16 Bs[256][32];  // 16 KB
  int tid = threadIdx.x;
  int lane = tid & 63, wid = tid >> 6;
  int wr = wid >> 1, wc = wid & 1;  // wave: 64 rows x 128 cols
  int m0 = blockIdx.y * 128, n0 = blockIdx.x * 256;
  int mr = lane & 15, quad = lane >> 4, kq = quad * 8;
  int srow = tid >> 2, scol = (tid & 3) * 8;

  f32x4 acc[4][8] = {};

  for (int k0 = 0; k0 < K; k0 += 32) {
    for (int i = 0; i < 2; i++) {
      int row = srow + i * 64;
      gl2lds16(&A[(size_t)(m0 + row) * K + k0 + scol], &As[row][scol]);
    }
    for (int i = 0; i < 4; i++) {
      int row = srow + i * 64;
      gl2lds16(&BT[(size_t)(n0 + row) * K + k0 + scol], &Bs[row][scol]);
    }
    __syncthreads();
    bf16x8 af[4], bfr[8];
    for (int i = 0; i < 4; i++) af[i] = *(bf16x8*)&As[wr * 64 + i * 16 + mr][kq];
    for (int j = 0; j < 8; j++) bfr[j] = *(bf16x8*)&Bs[wc * 128 + j * 16 + mr][kq];
    for (int i = 0; i < 4; i++)
      for (int j = 0; j < 8; j++)
        acc[i][j] = __builtin_amdgcn_mfma_f32_16x16x32_bf16(af[i], bfr[j], acc[i][j], 0, 0, 0);
    __syncthreads();
  }

  float ga = 0.f, gb = 0.f, gc = 0.f;
  if (EPI == 1) { ga = *c0p; gb = *c1p; gc = *c2p; }

  for (int i = 0; i < 4; i++) {
    for (int j = 0; j < 8; j++) {
      int col = n0 + wc * 128 + j * 16 + mr;
      float bv = bias[col];
      for (int r = 0; r < 4; r++) {
        int row = m0 + wr * 64 + i * 16 + quad * 4 + r;
        size_t idx = (size_t)row * N + col;
        float c = acc[i][j][r] + bv;
        if (EPI == 0) {
          ((__bf16*)outv)[idx] = (__bf16)c;
        } else {
          float u = (ga * c + gb) * c + gc;
          ((__bf16*)outv)[idx] = (__bf16)u;
        }
      }
    }
  }
}

// -------- flash-style polynomial attention: wave owns 64 q-rows (Q-tile 256) --------
// S^T = K*Q^T -> packed b64 P stores into Ps[q][key] (= PV A-fragment layout).
// kf/vf fragments amortized over 4 i-steps: LDS bytes per MFMA halved vs R5.
__global__ __launch_bounds__(256, 2) void attn_poly(const __bf16* __restrict__ qkv,
                                                    const __bf16* __restrict__ vt,
                                                    __bf16* __restrict__ outp,
                                                    const float* __restrict__ ap,
                                                    const float* __restrict__ bp,
                                                    const float* __restrict__ cp) {
  // Qs[256][72] aliases QPs[4][64][72] (wave w's Q rows == wave w's Ps region)
  __shared__ __bf16 QPs[4][64][72];  // 36,864 B
  __shared__ __bf16 Ks[64][72];      //  9,216 B
  __shared__ __bf16 Vts[64][72];     //  9,216 B
  __bf16(*Qs)[72] = (__bf16(*)[72]) & QPs[0][0][0];

  int tid = threadIdx.x, lane = tid & 63, wid = tid >> 6;
  int mr = lane & 15, quad = lane >> 4, kq = quad * 8;
  int q0 = blockIdx.x * 256;
  int h = blockIdx.y, b = blockIdx.z;
  int bh = b * 12 + h;
  size_t baseQ = ((size_t)b * 2048) * 2304 + h * 64;

  for (int i = 0; i < 8; i++) {
    int chunk = tid + i * 256;
    int row = chunk >> 3, dc = chunk & 7;
    *(bf16x8*)&Qs[row][dc * 8] =
        *(const bf16x8*)&qkv[baseQ + (size_t)(q0 + row) * 2304 + dc * 8];
  }
  __syncthreads();

  bf16x8 qf[4][2];  // B-operand: Q^T[d][q] == Q[q=mr][d]
  for (int i = 0; i < 4; i++)
    for (int s = 0; s < 2; s++)
      qf[i][s] = *(bf16x8*)&Qs[wid * 64 + i * 16 + mr][s * 32 + kq];

  float a2 = (*ap) * 0.015625f, b2 = (*bp) * 0.125f, cc = *cp;  // SCALE folded
  f32x4 o_acc[4][4] = {};
  float l_acc[4] = {0.f, 0.f, 0.f, 0.f};

  for (int kt = 0; kt < 32; kt++) {
    __syncthreads();  // A: Ks/Vts WAR
    for (int i = 0; i < 2; i++) {
      int chunk = tid + i * 256;
      int row = chunk >> 3, dc = chunk & 7;
      *(bf16x8*)&Ks[row][dc * 8] =
          *(const bf16x8*)&qkv[baseQ + (size_t)(kt * 64 + row) * 2304 + 768 + dc * 8];
      *(bf16x8*)&Vts[row][dc * 8] =
          *(const bf16x8*)&vt[((size_t)bh * 64 + row) * 2048 + kt * 64 + dc * 8];
    }
    __syncthreads();  // B: staging done

    bf16x8 kf[4][2];  // A-operand: K[key=mr][d]
    for (int j = 0; j < 4; j++)
      for (int s = 0; s < 2; s++)
        kf[j][s] = *(bf16x8*)&Ks[j * 16 + mr][s * 32 + kq];
    bf16x8 vf[2][4];  // B-operand for PV: V^T[d][key] rows
    for (int s = 0; s < 2; s++)
      for (int dt = 0; dt < 4; dt++)
        vf[s][dt] = *(bf16x8*)&Vts[dt * 16 + mr][s * 32 + kq];

    // S^T = K*Q^T -> poly -> packed b64 P stores (4 keys/lane)
    for (int i = 0; i < 4; i++) {
      f32x4 sacc[4] = {};
      for (int j = 0; j < 4; j++)
        for (int s = 0; s < 2; s++)
          sacc[j] = __builtin_amdgcn_mfma_f32_16x16x32_bf16(kf[j][s], qf[i][s], sacc[j], 0, 0, 0);
      float rsum = 0.f;
      for (int j = 0; j < 4; j++) {
        bf16x4 pk;
        for (int r = 0; r < 4; r++) {
          float S = sacc[j][r];
          float p = fmaf(fmaf(a2, S, b2), S, cc);
          p = fmaxf(p, 1e-6f);
          rsum += p;
          pk[r] = (__bf16)p;
        }
        *(bf16x4*)&QPs[wid][i * 16 + mr][j * 16 + quad * 4] = pk;
      }
      rsum += __shfl_xor(rsum, 16, 64);
      rsum += __shfl_xor(rsum, 32, 64);
      l_acc[i] += rsum;
    }

    __syncthreads();  // C: cross-lane Ps write->read

    // O += P*V
    for (int i = 0; i < 4; i++) {
      for (int s = 0; s < 2; s++) {
        bf16x8 pf = *(bf16x8*)&QPs[wid][i * 16 + mr][s * 32 + kq];
        for (int dt = 0; dt < 4; dt++)
          o_acc[i][dt] = __builtin_amdgcn_mfma_f32_16x16x32_bf16(pf, vf[s][dt], o_acc[i][dt], 0, 0, 0);
      }
    }
  }

  // epilogue: O C-layout [q = quad*4+r][d = mr]; l_acc indexed by q = mr
  size_t baseO = ((size_t)b * 2048) * 768 + h * 64;
  for (int i = 0; i < 4; i++) {
    float inv[4];
    for (int r = 0; r < 4; r++)
      inv[r] = 1.0f / (__shfl(l_acc[i], quad * 4 + r, 64) + 1e-8f);
    for (int dt = 0; dt < 4; dt++) {
      int q = q0 + wid * 64 + i * 16 + quad * 4;
      for (int r = 0; r < 4; r++) {
        outp[baseO + (size_t)(q + r) * 768 + dt * 16 + mr] =
            (__bf16)(o_acc[i][dt][r] * inv[r]);
      }
    }
  }
}

extern "C" void kernel_launch(void* const* d_in, const int* in_sizes, int n_in,
                              void* d_out, int out_size, void* d_ws, size_t ws_size,
                              hipStream_t stream) {
  const float* x     = (const float*)d_in[0];
  const float* ln1g  = (const float*)d_in[1];
  const float* ln1b  = (const float*)d_in[2];
  const float* ln2g  = (const float*)d_in[3];
  const float* ln2b  = (const float*)d_in[4];
  const float* qkvw  = (const float*)d_in[5];
  const float* qkvb  = (const float*)d_in[6];
  const float* projw = (const float*)d_in[7];
  const float* projb = (const float*)d_in[8];
  const float* fc1w  = (const float*)d_in[9];
  const float* fc1b  = (const float*)d_in[10];
  const float* fc2w  = (const float*)d_in[11];
  const float* fc2b  = (const float*)d_in[12];
  const float* attna = (const float*)d_in[13];
  const float* attnb = (const float*)d_in[14];
  const float* attnc = (const float*)d_in[15];
  const float* gelua = (const float*)d_in[16];
  const float* gelub = (const float*)d_in[17];
  const float* geluc = (const float*)d_in[18];

  char* ws = (char*)d_ws;
  __bf16* wT_qkv  = (__bf16*)(ws);             // [2304][768]  3,538,944 B
  __bf16* wT_proj = (__bf16*)(ws + 3538944);   // [768][768]   1,179,648 B
  __bf16* wT_fc1  = (__bf16*)(ws + 4718592);   // [3072][768]  4,718,592 B
  __bf16* wT_fc2  = (__bf16*)(ws + 9437184);   // [768][3072]  4,718,592 B
  __bf16* h       = (__bf16*)(ws + 14155776);  // [8192][768]  bf16 12,582,912 B
  float*  x1      = (float*)(ws + 26738688);   // [8192][768]  f32  25,165,824 B
  __bf16* qkvbuf  = (__bf16*)(ws + 51904512);  // [8192][2304] bf16 (dead after attn)
  __bf16* u       = (__bf16*)(ws + 51904512);  // [8192][3072] bf16 (overlaps qkv)
  __bf16* vtbuf   = (__bf16*)(ws + 89653248);  // [3072][2048] bf16 12,582,912 B
  float*  outp    = (float*)d_out;

  transpose_k<<<dim3(2304 / 32, 768 / 32), 256, 0, stream>>>(qkvw, wT_qkv, 768, 2304);
  transpose_k<<<dim3(768 / 32, 768 / 32), 256, 0, stream>>>(projw, wT_proj, 768, 768);
  transpose_k<<<dim3(3072 / 32, 768 / 32), 256, 0, stream>>>(fc1w, wT_fc1, 768, 3072);
  transpose_k<<<dim3(768 / 32, 3072 / 32), 256, 0, stream>>>(fc2w, wT_fc2, 3072, 768);

  ln_kernel<<<8192, 256, 0, stream>>>(x, ln1g, ln1b, h);
  gemm256<0><<<dim3(9, 64), 256, 0, stream>>>(h, wT_qkv, qkvb, qkvbuf,
                                              8192, 2304, 768, nullptr, nullptr, nullptr);
  transpose_v<<<dim3(64, 2, 48), 256, 0, stream>>>(qkvbuf, vtbuf);
  attn_poly<<<dim3(8, 12, 4), 256, 0, stream>>>(qkvbuf, vtbuf, h, attna, attnb, attnc);
  gemm128<2><<<dim3(6, 64), 256, 0, stream>>>(h, wT_proj, projb, x, x1,
                                              8192, 768, 768, nullptr, nullptr, nullptr);
  ln_kernel<<<8192, 256, 0, stream>>>(x1, ln2g, ln2b, h);
  gemm256<1><<<dim3(12, 64), 256, 0, stream>>>(h, wT_fc1, fc1b, u,
                                               8192, 3072, 768, gelua, gelub, geluc);
  gemm128<2><<<dim3(6, 64), 256, 0, stream>>>(u, wT_fc2, fc2b, x1, outp,
                                              8192, 768, 3072, nullptr, nullptr, nullptr);
}

// Round 7
// 411.262 us; speedup vs baseline: 1.1688x; 1.1688x over previous
//
#include <hip/hip_runtime.h>

typedef __bf16 bf16x8 __attribute__((ext_vector_type(8)));
typedef __bf16 bf16x4 __attribute__((ext_vector_type(4)));
typedef float f32x4 __attribute__((ext_vector_type(4)));

#define LN_EPS 1e-5f

// async global->LDS, 16B per lane (HW: wave-uniform LDS base + lane*16)
__device__ __forceinline__ void gl2lds16(const void* g, void* l) {
  __builtin_amdgcn_global_load_lds(
      (const __attribute__((address_space(1))) unsigned int*)g,
      (__attribute__((address_space(3))) unsigned int*)l, 16, 0, 0);
}

// -------- weight transpose + downcast: in f32 [R][C] -> out bf16 [C][R] --------
__global__ __launch_bounds__(256) void transpose_k(const float* __restrict__ in,
                                                   __bf16* __restrict__ out,
                                                   int R, int C) {
  __shared__ __bf16 t[32][33];
  int tx = threadIdx.x & 31, ty = threadIdx.x >> 5;  // 32x8
  int c = blockIdx.x * 32 + tx;
  for (int j = 0; j < 4; j++) {
    int r = blockIdx.y * 32 + ty + j * 8;
    t[ty + j * 8][tx] = (__bf16)in[(size_t)r * C + c];
  }
  __syncthreads();
  int r2 = blockIdx.y * 32 + tx;
  for (int j = 0; j < 4; j++) {
    int c2 = blockIdx.x * 32 + ty + j * 8;
    out[(size_t)c2 * R + r2] = t[tx][ty + j * 8];
  }
}

// -------- V transpose: qkv[token][2304] V-part -> vt[(b*12+h)*64+d][2048] --------
__global__ __launch_bounds__(256) void transpose_v(const __bf16* __restrict__ qkv,
                                                   __bf16* __restrict__ vt) {
  __shared__ __bf16 t[32][33];
  int bh = blockIdx.z;
  int b = bh / 12, h = bh % 12;
  int n0 = blockIdx.x * 32, d0 = blockIdx.y * 32;
  int tx = threadIdx.x & 31, ty = threadIdx.x >> 5;
  for (int j = 0; j < 4; j++) {
    int n = n0 + ty + j * 8;
    t[ty + j * 8][tx] = qkv[(size_t)(b * 2048 + n) * 2304 + 1536 + h * 64 + d0 + tx];
  }
  __syncthreads();
  for (int j = 0; j < 4; j++) {
    int d = d0 + ty + j * 8;
    vt[((size_t)bh * 64 + d) * 2048 + n0 + tx] = t[tx][ty + j * 8];
  }
}

// -------- layernorm over 768: f32 in -> bf16 out, one block per row --------
__global__ __launch_bounds__(256) void ln_kernel(const float* __restrict__ x,
                                                 const float* __restrict__ g,
                                                 const float* __restrict__ bta,
                                                 __bf16* __restrict__ out) {
  int row = blockIdx.x;
  size_t base = (size_t)row * 768;
  int t = threadIdx.x;
  float v[3];
  float s = 0.f, s2 = 0.f;
  for (int k = 0; k < 3; k++) {
    float f = x[base + t + k * 256];
    v[k] = f;
    s += f;
    s2 += f * f;
  }
  for (int m = 1; m < 64; m <<= 1) {
    s += __shfl_xor(s, m, 64);
    s2 += __shfl_xor(s2, m, 64);
  }
  __shared__ float sm[4][2];
  int wid = t >> 6, lane = t & 63;
  if (lane == 0) { sm[wid][0] = s; sm[wid][1] = s2; }
  __syncthreads();
  s = sm[0][0] + sm[1][0] + sm[2][0] + sm[3][0];
  s2 = sm[0][1] + sm[1][1] + sm[2][1] + sm[3][1];
  float mu = s * (1.f / 768.f);
  float var = s2 * (1.f / 768.f) - mu * mu;
  float rstd = rsqrtf(var + LN_EPS);
  for (int k = 0; k < 3; k++) {
    int c = t + k * 256;
    out[base + c] = (__bf16)((v[k] - mu) * rstd * g[c] + bta[c]);
  }
}

// -------- unified MFMA GEMM, BK=64, swizzled glds staging --------
// C[M,N] = A[M,K] @ BT[N,K]^T + bias. Tile 128 x NT.
// EPI 0: bf16 out = c ; EPI 1: bf16 poly-gelu ; EPI 2: f32 out = c + res
template <int NT, int EPI>
__global__ __launch_bounds__(256, (NT == 128 ? 3 : 2))
void gemm_bk64(const __bf16* __restrict__ A, const __bf16* __restrict__ BT,
               const float* __restrict__ bias, const float* __restrict__ res,
               void* __restrict__ outv, int M, int N, int K,
               const float* __restrict__ c0p, const float* __restrict__ c1p,
               const float* __restrict__ c2p) {
  // unpadded rows (128B) for glds; 16B chunks XOR-swizzled by (row&7) so
  // fragment b128 reads land 2-way on banks (free) instead of 16-way.
  __shared__ __bf16 As[128][64];
  __shared__ __bf16 Bs[NT][64];
  const int tid = threadIdx.x, lane = tid & 63, wid = tid >> 6;
  const int wr = wid >> 1, wc = wid & 1;
  const int mr = lane & 15, quad = lane >> 4;
  const int m0 = blockIdx.y * 128, n0 = blockIdx.x * NT;
  const int swzsrc = (((lane & 7) ^ ((lane >> 3) & 7)) * 8);  // source chunk for glds
  const int srow8 = lane >> 3;
  const int col0 = ((quad ^ (mr & 7)) * 8);        // kk=0 fragment chunk (elems)
  const int col1 = (((4 + quad) ^ (mr & 7)) * 8);  // kk=1

  f32x4 acc[4][NT / 32] = {};

  for (int k0 = 0; k0 < K; k0 += 64) {
    for (int g = 0; g < 4; g++) {
      int r0 = wid * 32 + g * 8 + srow8;
      gl2lds16(&A[(size_t)(m0 + r0) * K + k0 + swzsrc], &As[r0][(lane & 7) * 8]);
    }
    for (int g = 0; g < NT / 32; g++) {
      int r0 = wid * (NT / 4) + g * 8 + srow8;
      gl2lds16(&BT[(size_t)(n0 + r0) * K + k0 + swzsrc], &Bs[r0][(lane & 7) * 8]);
    }
    __syncthreads();  // drains glds (vmcnt)
    for (int kk = 0; kk < 2; kk++) {
      const int ck = kk ? col1 : col0;
      bf16x8 af[4], bfr[NT / 32];
      for (int i = 0; i < 4; i++) af[i] = *(bf16x8*)&As[wr * 64 + i * 16 + mr][ck];
      for (int j = 0; j < NT / 32; j++)
        bfr[j] = *(bf16x8*)&Bs[wc * (NT / 2) + j * 16 + mr][ck];
      for (int i = 0; i < 4; i++)
        for (int j = 0; j < NT / 32; j++)
          acc[i][j] = __builtin_amdgcn_mfma_f32_16x16x32_bf16(af[i], bfr[j], acc[i][j], 0, 0, 0);
    }
    __syncthreads();
  }

  float ga = 0.f, gb = 0.f, gc = 0.f;
  if (EPI == 1) { ga = *c0p; gb = *c1p; gc = *c2p; }

  for (int i = 0; i < 4; i++) {
    for (int j = 0; j < NT / 32; j++) {
      int col = n0 + wc * (NT / 2) + j * 16 + mr;
      float bv = bias[col];
      for (int r = 0; r < 4; r++) {
        int row = m0 + wr * 64 + i * 16 + quad * 4 + r;
        size_t idx = (size_t)row * N + col;
        float c = acc[i][j][r] + bv;
        if (EPI == 0) {
          ((__bf16*)outv)[idx] = (__bf16)c;
        } else if (EPI == 1) {
          float u = (ga * c + gb) * c + gc;
          ((__bf16*)outv)[idx] = (__bf16)u;
        } else {
          ((float*)outv)[idx] = c + res[idx];
        }
      }
    }
  }
}

// -------- flash-style polynomial attention v3 --------
// Wave owns 32 q-rows; block 128 q; grid (16,12,4)=768 (3 blocks/CU).
// Double-buffered K/V via glds (swizzled), prefetch issued AFTER the single
// per-iter barrier (full iter in flight). S^T=K*Q^T -> packed b64 P stores
// into per-wave Ps (A-fragment layout for PV); wave-internal lgkm fence.
__global__ __launch_bounds__(256, 3) void attn_poly(const __bf16* __restrict__ qkv,
                                                    const __bf16* __restrict__ vt,
                                                    __bf16* __restrict__ outp,
                                                    const float* __restrict__ ap,
                                                    const float* __restrict__ bp,
                                                    const float* __restrict__ cp) {
  __shared__ __bf16 Ps[4][32][72];   // 18,432 B (per-wave regions, padded)
  __shared__ __bf16 Kb[2][64][64];   // 16,384 B (unpadded, swizzled chunks)
  __shared__ __bf16 Vb[2][64][64];   // 16,384 B

  const int tid = threadIdx.x, lane = tid & 63, wid = tid >> 6;
  const int mr = lane & 15, quad = lane >> 4;
  const int q0 = blockIdx.x * 128;
  const int h = blockIdx.y, b = blockIdx.z;
  const int bh = b * 12 + h;
  const size_t baseQ = ((size_t)b * 2048) * 2304 + h * 64;

  const int swzsrc = (((lane & 7) ^ ((lane >> 3) & 7)) * 8);
  const int srow8 = lane >> 3;
  const int colS0 = ((quad ^ (mr & 7)) * 8);        // s=0 fragment chunk
  const int colS1 = (((4 + quad) ^ (mr & 7)) * 8);  // s=1

  // Q fragments straight from global (one-time; B-operand Q^T[d][q]=Q[q=mr][d])
  bf16x8 qf[2][2];
  for (int i = 0; i < 2; i++)
    for (int s = 0; s < 2; s++)
      qf[i][s] = *(const bf16x8*)&qkv[baseQ + (size_t)(q0 + wid * 32 + i * 16 + mr) * 2304 +
                                      s * 32 + quad * 8];

  const float a2 = (*ap) * 0.015625f, b2 = (*bp) * 0.125f, cc = *cp;  // SCALE folded
  f32x4 o_acc[2][4] = {};
  float l_acc[2] = {0.f, 0.f};

  // stage tile kt into buffer pb (wave w covers rows 16w..16w+15 of K and V)
  auto stage = [&](int kt, int pb) {
    for (int g = 0; g < 2; g++) {
      int r0 = wid * 16 + g * 8 + srow8;
      gl2lds16(&qkv[baseQ + (size_t)(kt * 64 + r0) * 2304 + 768 + swzsrc],
               &Kb[pb][r0][(lane & 7) * 8]);
      gl2lds16(&vt[((size_t)bh * 64 + r0) * 2048 + kt * 64 + swzsrc],
               &Vb[pb][r0][(lane & 7) * 8]);
    }
  };

  stage(0, 0);
  int pb = 0;
  for (int kt = 0; kt < 32; kt++) {
    __syncthreads();                       // drains prefetch(kt); Ps WAR via wave order
    if (kt < 31) stage(kt + 1, pb ^ 1);    // async: a full iteration in flight

    // S^T = K * Q^T  (A = K[key][d], B = Q^T)
    f32x4 sacc[2][4] = {};
    for (int j = 0; j < 4; j++) {
      for (int s = 0; s < 2; s++) {
        bf16x8 kf = *(bf16x8*)&Kb[pb][j * 16 + mr][s ? colS1 : colS0];
        for (int i = 0; i < 2; i++)
          sacc[i][j] = __builtin_amdgcn_mfma_f32_16x16x32_bf16(kf, qf[i][s], sacc[i][j], 0, 0, 0);
      }
    }
    // poly + clamp + packed b64 P stores (4 consecutive keys per lane) + row-sums
    for (int i = 0; i < 2; i++) {
      f32x4 racc = {0.f, 0.f, 0.f, 0.f};
      for (int j = 0; j < 4; j++) {
        f32x4 S = sacc[i][j];
        f32x4 p = (a2 * S + b2) * S + cc;
        p[0] = fmaxf(p[0], 1e-6f); p[1] = fmaxf(p[1], 1e-6f);
        p[2] = fmaxf(p[2], 1e-6f); p[3] = fmaxf(p[3], 1e-6f);
        racc += p;
        bf16x4 pk = {(__bf16)p[0], (__bf16)p[1], (__bf16)p[2], (__bf16)p[3]};
        *(bf16x4*)&Ps[wid][i * 16 + mr][j * 16 + quad * 4] = pk;
      }
      float rsum = racc[0] + racc[1] + racc[2] + racc[3];
      rsum += __shfl_xor(rsum, 16, 64);
      rsum += __shfl_xor(rsum, 32, 64);
      l_acc[i] += rsum;
    }

    // wave-internal cross-lane P dependency: DS ops complete in order per wave;
    // fence stops compiler reordering and waits the writes.
    __asm__ __volatile__("s_waitcnt lgkmcnt(0)" ::: "memory");

    // O += P * V  (A = Ps[q][key] b128, B = V[key][d] via Vb[d][key])
    for (int s = 0; s < 2; s++) {
      bf16x8 pf[2];
      for (int i = 0; i < 2; i++)
        pf[i] = *(bf16x8*)&Ps[wid][i * 16 + mr][s * 32 + quad * 8];
      for (int dt = 0; dt < 4; dt++) {
        bf16x8 vf = *(bf16x8*)&Vb[pb][dt * 16 + mr][s ? colS1 : colS0];
        for (int i = 0; i < 2; i++)
          o_acc[i][dt] = __builtin_amdgcn_mfma_f32_16x16x32_bf16(pf[i], vf, o_acc[i][dt], 0, 0, 0);
      }
    }
    __asm__ __volatile__("" ::: "memory");  // keep next iter's Ps writes after these reads
    pb ^= 1;
  }

  // epilogue: O C-layout [q = quad*4+r][d = mr]; l_acc indexed by q = mr
  size_t baseO = ((size_t)b * 2048) * 768 + h * 64;
  for (int i = 0; i < 2; i++) {
    float inv[4];
    for (int r = 0; r < 4; r++)
      inv[r] = 1.0f / (__shfl(l_acc[i], quad * 4 + r, 64) + 1e-8f);
    for (int dt = 0; dt < 4; dt++) {
      int q = q0 + wid * 32 + i * 16 + quad * 4;
      for (int r = 0; r < 4; r++)
        outp[baseO + (size_t)(q + r) * 768 + dt * 16 + mr] =
            (__bf16)(o_acc[i][dt][r] * inv[r]);
    }
  }
}

extern "C" void kernel_launch(void* const* d_in, const int* in_sizes, int n_in,
                              void* d_out, int out_size, void* d_ws, size_t ws_size,
                              hipStream_t stream) {
  const float* x     = (const float*)d_in[0];
  const float* ln1g  = (const float*)d_in[1];
  const float* ln1b  = (const float*)d_in[2];
  const float* ln2g  = (const float*)d_in[3];
  const float* ln2b  = (const float*)d_in[4];
  const float* qkvw  = (const float*)d_in[5];
  const float* qkvb  = (const float*)d_in[6];
  const float* projw = (const float*)d_in[7];
  const float* projb = (const float*)d_in[8];
  const float* fc1w  = (const float*)d_in[9];
  const float* fc1b  = (const float*)d_in[10];
  const float* fc2w  = (const float*)d_in[11];
  const float* fc2b  = (const float*)d_in[12];
  const float* attna = (const float*)d_in[13];
  const float* attnb = (const float*)d_in[14];
  const float* attnc = (const float*)d_in[15];
  const float* gelua = (const float*)d_in[16];
  const float* gelub = (const float*)d_in[17];
  const float* geluc = (const float*)d_in[18];

  char* ws = (char*)d_ws;
  __bf16* wT_qkv  = (__bf16*)(ws);             // [2304][768]  3,538,944 B
  __bf16* wT_proj = (__bf16*)(ws + 3538944);   // [768][768]   1,179,648 B
  __bf16* wT_fc1  = (__bf16*)(ws + 4718592);   // [3072][768]  4,718,592 B
  __bf16* wT_fc2  = (__bf16*)(ws + 9437184);   // [768][3072]  4,718,592 B
  __bf16* h       = (__bf16*)(ws + 14155776);  // [8192][768]  bf16 12,582,912 B
  float*  x1      = (float*)(ws + 26738688);   // [8192][768]  f32  25,165,824 B
  __bf16* qkvbuf  = (__bf16*)(ws + 51904512);  // [8192][2304] bf16 (dead after attn)
  __bf16* u       = (__bf16*)(ws + 51904512);  // [8192][3072] bf16 (overlaps qkv)
  __bf16* vtbuf   = (__bf16*)(ws + 89653248);  // [3072][2048] bf16 12,582,912 B
  float*  outp    = (float*)d_out;

  transpose_k<<<dim3(2304 / 32, 768 / 32), 256, 0, stream>>>(qkvw, wT_qkv, 768, 2304);
  transpose_k<<<dim3(768 / 32, 768 / 32), 256, 0, stream>>>(projw, wT_proj, 768, 768);
  transpose_k<<<dim3(3072 / 32, 768 / 32), 256, 0, stream>>>(fc1w, wT_fc1, 768, 3072);
  transpose_k<<<dim3(768 / 32, 3072 / 32), 256, 0, stream>>>(fc2w, wT_fc2, 3072, 768);

  ln_kernel<<<8192, 256, 0, stream>>>(x, ln1g, ln1b, h);
  gemm_bk64<256, 0><<<dim3(9, 64), 256, 0, stream>>>(h, wT_qkv, qkvb, nullptr, qkvbuf,
                                                     8192, 2304, 768, nullptr, nullptr, nullptr);
  transpose_v<<<dim3(64, 2, 48), 256, 0, stream>>>(qkvbuf, vtbuf);
  attn_poly<<<dim3(16, 12, 4), 256, 0, stream>>>(qkvbuf, vtbuf, h, attna, attnb, attnc);
  gemm_bk64<128, 2><<<dim3(6, 64), 256, 0, stream>>>(h, wT_proj, projb, x, x1,
                                                     8192, 768, 768, nullptr, nullptr, nullptr);
  ln_kernel<<<8192, 256, 0, stream>>>(x1, ln2g, ln2b, h);
  gemm_bk64<256, 1><<<dim3(12, 64), 256, 0, stream>>>(h, wT_fc1, fc1b, nullptr, u,
                                                      8192, 3072, 768, gelua, gelub, geluc);
  gemm_bk64<128, 2><<<dim3(6, 64), 256, 0, stream>>>(u, wT_fc2, fc2b, x1, outp,
                                                     8192, 768, 3072, nullptr, nullptr, nullptr);
}